// Round 1
// baseline (243.828 us; speedup 1.0000x reference)
//
#include <hip/hip_runtime.h>
#include <math.h>

// Problem constants (fixed by reference setup_inputs)
#define T_TOK 16384
#define DDIM  2048
#define NE    64
#define NPLANE (NE * DDIM)      // 131072 elements per W split plane
#define NBLK  512               // main-kernel grid (32 tokens each)

typedef __attribute__((ext_vector_type(8))) short short8;   // 8 bf16 MFMA frag
typedef __attribute__((ext_vector_type(4))) float floatx4;  // MFMA C/D

union Frag8 { unsigned short u[8]; short8 v; };

__device__ __forceinline__ unsigned int bf16_rne_bits(float x) {
    unsigned int u = __builtin_bit_cast(unsigned int, x);
    return (u + 0x7fffu + ((u >> 16) & 1u)) & 0xffff0000u;
}

// ---- pre-kernel: exact 3-way bf16 split of W (fp32 = h + m + l) ----
__global__ void wsplit_kernel(const float* __restrict__ W,
                              unsigned short* __restrict__ wh,
                              unsigned short* __restrict__ wm,
                              unsigned short* __restrict__ wl) {
    int i = blockIdx.x * 256 + threadIdx.x;   // grid covers exactly NPLANE
    float w = W[i];
    unsigned int hb = bf16_rne_bits(w);
    float r  = w - __builtin_bit_cast(float, hb);   // exact
    unsigned int mb = bf16_rne_bits(r);
    float r2 = r - __builtin_bit_cast(float, mb);   // exact
    unsigned int lb = bf16_rne_bits(r2);            // |err| <= 2^-24 |w|
    wh[i] = (unsigned short)(hb >> 16);
    wm[i] = (unsigned short)(mb >> 16);
    wl[i] = (unsigned short)(lb >> 16);
}

// ---- main: barrier-free K-loop, direct global->reg A frags ----
// Block: 512 thr = 8 waves; wave wv owns 32 tokens x 64 experts x 256-k
// slice (k in [wv*256, wv*256+256)). Every x element is loaded+split by
// exactly one wave -> no LDS staging, no __syncthreads in the K loop.
// LDS only for the epilogue logit exchange: lg[8][32][64] f32 = 64 KB.
__global__ __launch_bounds__(512, 4)
void router_main(const float* __restrict__ x,
                 const unsigned short* __restrict__ wh,
                 const unsigned short* __restrict__ wm,
                 const unsigned short* __restrict__ wl,
                 float* __restrict__ out, float* __restrict__ usage_part) {
    __shared__ float lg[8 * 2048];     // [kq][token32][expert64], 64 KB
    __shared__ float ured[8][NE];      // 2 KB

    const int tid  = threadIdx.x;
    const int lane = tid & 63;
    const int wv   = __builtin_amdgcn_readfirstlane(tid >> 6);  // 0..7 = kq
    const int cl   = lane & 15;  // frag row index (token / expert)
    const int q    = lane >> 4;  // frag k-quad
    const int t0   = blockIdx.x * 32;

    // A frag source: token row t0 + mt*16 + cl, k = wv*256 + c*32 + q*8 + j
    // (16x16x32 A layout: row = lane&15, k = (lane>>4)*8 + j, j contiguous)
    const float* xa = x + (size_t)(t0 + cl) * DDIM + wv * 256 + q * 8;
    // B frag source: expert row nt*16 + cl, same k (L2-resident planes)
    const size_t bb = (size_t)cl * DDIM + wv * 256 + q * 8;

    floatx4 acc[2][4];
#pragma unroll
    for (int mt = 0; mt < 2; ++mt)
#pragma unroll
        for (int nt = 0; nt < 4; ++nt)
            acc[mt][nt] = (floatx4){0.f, 0.f, 0.f, 0.f};

#pragma unroll
    for (int c = 0; c < 8; ++c) {    // 8 K-steps of 32
        const int ko = c * 32;

        // B frags first: 12 x 16B loads in flight while the A split runs
        uint4 cb[4][3];
#pragma unroll
        for (int nt = 0; nt < 4; ++nt) {
            const size_t o = bb + (size_t)nt * 16 * DDIM + ko;
            cb[nt][0] = *(const uint4*)(wh + o);
            cb[nt][1] = *(const uint4*)(wm + o);
            cb[nt][2] = *(const uint4*)(wl + o);
        }

        // A frags: direct global->reg + exact truncation 3-way split
        short8 Ah[2], Am[2], Al[2];
#pragma unroll
        for (int mt = 0; mt < 2; ++mt) {
            const float* ap = xa + (size_t)mt * 16 * DDIM + ko;
            float4 a0 = *(const float4*)(ap);       // k j=0..3
            float4 a1 = *(const float4*)(ap + 4);   // k j=4..7
            float f[8] = {a0.x, a0.y, a0.z, a0.w, a1.x, a1.y, a1.z, a1.w};
            Frag8 fh, fm, fl;
#pragma unroll
            for (int j = 0; j < 8; ++j) {
                unsigned int ub = __builtin_bit_cast(unsigned int, f[j]);
                unsigned int hb = ub & 0xffff0000u;
                float r = f[j] - __builtin_bit_cast(float, hb);   // exact
                unsigned int rb = __builtin_bit_cast(unsigned int, r);
                unsigned int mb = rb & 0xffff0000u;
                float r2 = r - __builtin_bit_cast(float, mb);     // exact
                unsigned int lb = __builtin_bit_cast(unsigned int, r2);
                fh.u[j] = (unsigned short)(hb >> 16);
                fm.u[j] = (unsigned short)(mb >> 16);
                fl.u[j] = (unsigned short)(lb >> 16);
            }
            Ah[mt] = fh.v; Am[mt] = fm.v; Al[mt] = fl.v;
        }

        // 6 passes: hh + hm + mh + mm + hl + lh (error ~2^-24, as verified)
#pragma unroll
        for (int mt = 0; mt < 2; ++mt)
#pragma unroll
            for (int nt = 0; nt < 4; ++nt) {
                short8 Bh = __builtin_bit_cast(short8, cb[nt][0]);
                short8 Bm = __builtin_bit_cast(short8, cb[nt][1]);
                short8 Bl = __builtin_bit_cast(short8, cb[nt][2]);
                floatx4 a = acc[mt][nt];
                a = __builtin_amdgcn_mfma_f32_16x16x32_bf16(Ah[mt], Bh, a, 0, 0, 0);
                a = __builtin_amdgcn_mfma_f32_16x16x32_bf16(Ah[mt], Bm, a, 0, 0, 0);
                a = __builtin_amdgcn_mfma_f32_16x16x32_bf16(Am[mt], Bh, a, 0, 0, 0);
                a = __builtin_amdgcn_mfma_f32_16x16x32_bf16(Am[mt], Bm, a, 0, 0, 0);
                a = __builtin_amdgcn_mfma_f32_16x16x32_bf16(Ah[mt], Bl, a, 0, 0, 0);
                a = __builtin_amdgcn_mfma_f32_16x16x32_bf16(Al[mt], Bh, a, 0, 0, 0);
                acc[mt][nt] = a;
            }
    }

    // partial logits -> LDS. D layout: n(expert)=lane&15, m(token)=q*4+reg
#pragma unroll
    for (int mt = 0; mt < 2; ++mt)
#pragma unroll
        for (int nt = 0; nt < 4; ++nt)
#pragma unroll
            for (int r = 0; r < 4; ++r)
                lg[wv * 2048 + (mt * 16 + q * 4 + r) * 64 + nt * 16 + cl]
                    = acc[mt][nt][r];
    __syncthreads();   // the ONLY barrier in the kernel

    // ---- epilogue (verified previous session): lane = expert, 4 tok/wave ----
    float usage_acc = 0.f;
#pragma unroll 1
    for (int j = 0; j < 4; ++j) {
        const int tl = wv * 4 + j;
        const int t  = t0 + tl;
        float l = (((lg[0 * 2048 + tl * 64 + lane] + lg[1 * 2048 + tl * 64 + lane]) +
                    (lg[2 * 2048 + tl * 64 + lane] + lg[3 * 2048 + tl * 64 + lane])) +
                   ((lg[4 * 2048 + tl * 64 + lane] + lg[5 * 2048 + tl * 64 + lane]) +
                    (lg[6 * 2048 + tl * 64 + lane] + lg[7 * 2048 + tl * 64 + lane])));

        float v1 = l; int i1 = lane;
#pragma unroll
        for (int off = 32; off >= 1; off >>= 1) {
            float ov = __shfl_xor(v1, off, 64);
            int   oi = __shfl_xor(i1, off, 64);
            if (ov > v1 || (ov == v1 && oi < i1)) { v1 = ov; i1 = oi; }
        }
        float lm = (lane == i1) ? -INFINITY : l;
        float v2 = lm; int i2 = lane;
#pragma unroll
        for (int off = 32; off >= 1; off >>= 1) {
            float ov = __shfl_xor(v2, off, 64);
            int   oi = __shfl_xor(i2, off, 64);
            if (ov > v2 || (ov == v2 && oi < i2)) { v2 = ov; i2 = oi; }
        }

        float p = expf(l - v1);
        float s = p;
#pragma unroll
        for (int off = 32; off >= 1; off >>= 1) s += __shfl_xor(s, off, 64);

        float e2  = expf(v2 - v1);
        float rcp = 1.0f / (1.0f + e2);
        usage_acc += p / s;

        if (lane == 0) {
            out[(size_t)t * 2 + 0]         = (float)i1;
            out[(size_t)t * 2 + 1]         = (float)i2;
            out[32768 + (size_t)t * 2 + 0] = rcp;
            out[32768 + (size_t)t * 2 + 1] = e2 * rcp;
        }
    }

    // per-block usage partials (no atomics; deterministic)
    ured[wv][lane] = usage_acc;
    __syncthreads();
    if (wv == 0) {
        float s = ((ured[0][lane] + ured[1][lane]) + (ured[2][lane] + ured[3][lane])) +
                  ((ured[4][lane] + ured[5][lane]) + (ured[6][lane] + ured[7][lane]));
        usage_part[(size_t)blockIdx.x * 64 + lane] = s;
    }
}

__global__ __launch_bounds__(1024)
void router_aux(const float* __restrict__ usage_part, float* __restrict__ out) {
    __shared__ float red[16][NE];
    const int tid = threadIdx.x;    // 1024
    const int e   = tid & 63;
    const int g   = tid >> 6;       // 0..15
    float s = 0.f;
#pragma unroll
    for (int i = 0; i < NBLK / 16; ++i)
        s += usage_part[(size_t)(g * (NBLK / 16) + i) * 64 + e];
    red[g][e] = s;
    __syncthreads();
    if (g == 0) {
        float tot = 0.f;
#pragma unroll
        for (int i = 0; i < 16; ++i) tot += red[i][e];
        float u = tot * (1.0f / 16384.0f) - (1.0f / 64.0f);
        float sq = u * u;
#pragma unroll
        for (int off = 32; off >= 1; off >>= 1) sq += __shfl_xor(sq, off, 64);
        if (e == 0) out[65536] = sq;
    }
}

extern "C" void kernel_launch(void* const* d_in, const int* in_sizes, int n_in,
                              void* d_out, int out_size, void* d_ws, size_t ws_size,
                              hipStream_t stream) {
    const float* x = (const float*)d_in[0];   // [4,4096,2048] fp32
    const float* W = (const float*)d_in[1];   // [64,2048] fp32
    float* out     = (float*)d_out;           // 65537 floats

    // ws layout: Wh | Wm | Wl (bf16 planes, 256 KB each) | usage partials (128 KB)
    unsigned short* ws_h = (unsigned short*)d_ws;
    unsigned short* ws_m = ws_h + NPLANE;
    unsigned short* ws_l = ws_m + NPLANE;
    float* upart         = (float*)(ws_l + NPLANE);

    wsplit_kernel<<<dim3(NPLANE / 256), dim3(256), 0, stream>>>(W, ws_h, ws_m, ws_l);
    router_main<<<dim3(NBLK), dim3(512), 0, stream>>>(x, ws_h, ws_m, ws_l, out, upart);
    router_aux<<<dim3(1), dim3(1024), 0, stream>>>(upart, out);
}